// Round 3
// baseline (1711.139 us; speedup 1.0000x reference)
//
#include <hip/hip_runtime.h>
#include <hip/hip_bf16.h>

#define N_TOK 16384
#define DIM   1024
#define NEXP  4
#define HID   4096

typedef __attribute__((ext_vector_type(8))) short short8;
typedef __attribute__((ext_vector_type(4))) short short4v;
typedef __attribute__((ext_vector_type(4))) float float4v;

static __device__ __forceinline__ short f2bf(float f) {
  __hip_bfloat16 h = __float2bfloat16(f);
  return *reinterpret_cast<short*>(&h);
}

#define GLOAD_LDS16(gsrc, ldst)                                                            \
  __builtin_amdgcn_global_load_lds((const __attribute__((address_space(1))) void*)(gsrc),  \
                                   (__attribute__((address_space(3))) void*)(ldst), 16, 0, 0)

// ---------------- gate: softmax(concat(q,k) @ Wg + bg) ----------------
__global__ void gate_kernel(const float* __restrict__ q, const float* __restrict__ k,
                            const float* __restrict__ Wg, const float* __restrict__ bg,
                            float* __restrict__ gate) {
  const int wave = threadIdx.x >> 6, lane = threadIdx.x & 63;
  const int n = blockIdx.x * 4 + wave;
  const float* qr = q + (size_t)n * DIM;
  const float* kr = k + (size_t)n * DIM;
  float s0 = 0.f, s1 = 0.f, s2 = 0.f, s3 = 0.f;
  for (int i = 0; i < DIM / 64; ++i) {
    int d = i * 64 + lane;
    float x = qr[d];
    float4 w = *(const float4*)(Wg + (size_t)d * 4);
    s0 += x * w.x; s1 += x * w.y; s2 += x * w.z; s3 += x * w.w;
    float y = kr[d];
    float4 w2 = *(const float4*)(Wg + (size_t)(DIM + d) * 4);
    s0 += y * w2.x; s1 += y * w2.y; s2 += y * w2.z; s3 += y * w2.w;
  }
  for (int off = 32; off; off >>= 1) {
    s0 += __shfl_xor(s0, off);
    s1 += __shfl_xor(s1, off);
    s2 += __shfl_xor(s2, off);
    s3 += __shfl_xor(s3, off);
  }
  if (lane == 0) {
    float l0 = s0 + bg[0], l1 = s1 + bg[1], l2 = s2 + bg[2], l3 = s3 + bg[3];
    float m = fmaxf(fmaxf(l0, l1), fmaxf(l2, l3));
    float e0 = expf(l0 - m), e1 = expf(l1 - m), e2 = expf(l2 - m), e3 = expf(l3 - m);
    float inv = 1.f / (e0 + e1 + e2 + e3);
    float4 g; g.x = e0 * inv; g.y = e1 * inv; g.z = e2 * inv; g.w = e3 * inv;
    *(float4*)(gate + (size_t)n * 4) = g;
  }
}

// ---------------- f32 -> bf16 straight convert ----------------
__global__ void convert_bf16_kernel(const float* __restrict__ in, short* __restrict__ out, int n4) {
  int stride = gridDim.x * blockDim.x;
  for (int i = blockIdx.x * blockDim.x + threadIdx.x; i < n4; i += stride) {
    float4 v = *(const float4*)(in + (size_t)i * 4);
    short4v o;
    o[0] = f2bf(v.x); o[1] = f2bf(v.y); o[2] = f2bf(v.z); o[3] = f2bf(v.w);
    *(short4v*)(out + (size_t)i * 4) = o;
  }
}

// ---- LDS-tiled transpose+convert: in[z][R][C] f32 -> out[z*z_row + c][z*z_col + r] bf16 ----
__global__ void transpose_bf16_kernel(const float* __restrict__ in, short* __restrict__ out,
                                      int R, int C, int ldo, int z_row, int z_col) {
  __shared__ float tile[64][65];
  const int z = blockIdx.z;
  const float* src = in + (size_t)z * R * C;
  const int r0 = blockIdx.y * 64, c0 = blockIdx.x * 64;
  const int tc = threadIdx.x & 63, tr = threadIdx.x >> 6;
#pragma unroll
  for (int p = 0; p < 16; ++p) {
    int r = p * 4 + tr;
    tile[r][tc] = src[(size_t)(r0 + r) * C + (c0 + tc)];
  }
  __syncthreads();
#pragma unroll
  for (int p = 0; p < 16; ++p) {
    int i = p * 4 + tr;
    out[(size_t)(z * z_row + c0 + i) * ldo + z * z_col + (r0 + tc)] = f2bf(tile[tc][i]);
  }
}

// ================= 256x256 8-wave bf16 MFMA GEMM, counted-vmcnt half-tile pipeline ==========
// LDS per operand: [buf p][khalf][256 rows][32 k] shorts (2 bufs). 16KB half-tile = 2 gloads.
// Swizzle: 16B chunk index ^= (row>>1)&3 (2-way bank aliasing = free). Inverse on global src.
// Per K-tile t (4 phases): ph0 (kk0,mh0)+stage A-kh1(t+1); ph1 (kk0,mh1)+stage B-kh1(t+1);
// ph2 (kk1,mh0)+stage A-kh0(t+2); ph3 (kk1,mh1)+stage B-kh0(t+2); then ONE vmcnt(4).
template <int KK, int MH, bool RB>
__device__ __forceinline__ void phase_fn(const short* sAp, const short* sBp, int p,
                                         int aBase, int bBase,
                                         short8 (&af)[4], short8 (&bf)[4],
                                         float4v (&acc)[8][4]) {
  const int ao = (p << 14) + (KK << 13) + MH * 2048 + aBase;
#pragma unroll
  for (int i = 0; i < 4; ++i) af[i] = *(const short8*)(sAp + ao + i * 512);
  if (RB) {
    const int bo = (p << 14) + (KK << 13) + bBase;
#pragma unroll
    for (int n = 0; n < 4; ++n) bf[n] = *(const short8*)(sBp + bo + n * 512);
  }
  __builtin_amdgcn_s_barrier();
  asm volatile("s_waitcnt lgkmcnt(0)" ::: "memory");
  __builtin_amdgcn_sched_barrier(0);
  __builtin_amdgcn_s_setprio(1);
#pragma unroll
  for (int i = 0; i < 4; ++i)
#pragma unroll
    for (int n = 0; n < 4; ++n)
      acc[MH * 4 + i][n] =
          __builtin_amdgcn_mfma_f32_16x16x32_bf16(af[i], bf[n], acc[MH * 4 + i][n], 0, 0, 0);
  __builtin_amdgcn_s_setprio(0);
  __builtin_amdgcn_sched_barrier(0);
}

template <int MODE>
__global__ __launch_bounds__(512, 2)
void gemm256(const short* __restrict__ A, const short* __restrict__ Bt,
             int K, int lda, int ldb, int NTN,
             const float* __restrict__ bias, const float* __restrict__ gate,
             int ecol_off, int e0, int eg, int accum,
             short* __restrict__ OutB, float* __restrict__ OutF, int ldc) {
  __shared__ short sA[32768];  // 2 bufs x 2 khalf x 256x32
  __shared__ short sB[32768];

  const int nwg = gridDim.x;
  const int NTM = nwg / NTN;
  // bijective XCD swizzle (m204)
  int bid = blockIdx.x;
  int qd = nwg >> 3, rm = nwg & 7;
  int xcd = bid & 7, idx = bid >> 3;
  int swz = (xcd < rm ? xcd * (qd + 1) : rm * (qd + 1) + (xcd - rm) * qd) + idx;
  // grouped 2D order: groups of 8 m-rows
  const int tpg = 8 * NTN;
  int g = swz / tpg;
  int lg = swz % tpg;
  int gm0 = g * 8;
  int gsz = NTM - gm0; if (gsz > 8) gsz = 8;
  const int tile_m = gm0 + lg % gsz;
  const int tile_n = lg / gsz;
  const int m0 = tile_m * 256;
  const int n0 = tile_n * 256;

  const int tid = threadIdx.x;
  const int lane = tid & 63;
  const int wid = tid >> 6;
  const int wm = wid >> 2, wn = wid & 3;
  const int r16 = lane & 15, kg = lane >> 4;
  // ds_read swizzled chunk: kg ^ ((row>>1)&3); row = 16*c + r16 -> key = (r16>>1)&3
  const int swc8 = ((kg ^ ((r16 >> 1) & 3)) << 3);
  const int aBase = (wm * 128 + r16) * 32 + swc8;
  const int bBase = (wn * 64 + r16) * 32 + swc8;
  // staging: thread tid covers rows (tid>>2) and 128+(tid>>2), chunk (tid&3) of LDS;
  // global source chunk = (tid&3) ^ ((row>>1)&3) = (tid&3) ^ ((tid>>3)&3)
  const int rowStage = tid >> 2;
  const int cg8 = (((tid & 3) ^ ((tid >> 3) & 3)) << 3);
  const int st8 = tid * 8;

  const short* aStage = A + (size_t)(m0 + rowStage) * lda + cg8;
  const short* bStage = Bt + (size_t)(n0 + rowStage) * ldb + cg8;

#define STG_A(t, kh)                                              \
  do {                                                            \
    const short* g_ = aStage + (t) * 64 + (kh) * 32;              \
    int l_ = ((((t) & 1) << 14) | ((kh) << 13)) + st8;            \
    GLOAD_LDS16(g_, sA + l_);                                     \
    GLOAD_LDS16(g_ + (size_t)128 * lda, sA + l_ + 4096);          \
  } while (0)
#define STG_B(t, kh)                                              \
  do {                                                            \
    const short* g_ = bStage + (t) * 64 + (kh) * 32;              \
    int l_ = ((((t) & 1) << 14) | ((kh) << 13)) + st8;            \
    GLOAD_LDS16(g_, sB + l_);                                     \
    GLOAD_LDS16(g_ + (size_t)128 * ldb, sB + l_ + 4096);          \
  } while (0)

  float4v acc[8][4];
#pragma unroll
  for (int m = 0; m < 8; ++m)
#pragma unroll
    for (int n = 0; n < 4; ++n) acc[m][n] = (float4v)0.0f;

  const int T = K >> 6;
  // prologue: T0 fully + T1-kh0; wait leaves T1-kh0 (4 loads) in flight
  STG_A(0, 0); STG_B(0, 0); STG_A(0, 1); STG_B(0, 1);
  if (T > 1) { STG_A(1, 0); STG_B(1, 0); }
  if (T > 1) asm volatile("s_waitcnt vmcnt(4)" ::: "memory");
  else       asm volatile("s_waitcnt vmcnt(0)" ::: "memory");
  __builtin_amdgcn_sched_barrier(0);
  __builtin_amdgcn_s_barrier();

  short8 af[4], bf[4];
  for (int t = 0; t < T; ++t) {
    const int p = t & 1;
    const bool s1 = (t + 1 < T), s2 = (t + 2 < T);
    // phase 0: (kk0, mh0); stage A-kh1(t+1)  [slot read last in tile t-1 ph2/3]
    if (s1) STG_A(t + 1, 1);
    phase_fn<0, 0, true>(sA, sB, p, aBase, bBase, af, bf, acc);
    __builtin_amdgcn_s_barrier();
    // phase 1: (kk0, mh1); stage B-kh1(t+1)
    if (s1) STG_B(t + 1, 1);
    phase_fn<0, 1, false>(sA, sB, p, aBase, bBase, af, bf, acc);
    __builtin_amdgcn_s_barrier();
    // phase 2: (kk1, mh0); stage A-kh0(t+2)  [kh0 of buf p free after ph1 barrier]
    if (s2) STG_A(t + 2, 0);
    phase_fn<1, 0, true>(sA, sB, p, aBase, bBase, af, bf, acc);
    __builtin_amdgcn_s_barrier();
    // phase 3: (kk1, mh1); stage B-kh0(t+2); counted tile-boundary wait
    if (s2) STG_B(t + 2, 0);
    phase_fn<1, 1, false>(sA, sB, p, aBase, bBase, af, bf, acc);
    if (s2) asm volatile("s_waitcnt vmcnt(4)" ::: "memory");
    else    asm volatile("s_waitcnt vmcnt(0)" ::: "memory");
    __builtin_amdgcn_sched_barrier(0);
    __builtin_amdgcn_s_barrier();
  }
#undef STG_A
#undef STG_B

  // epilogue: C/D layout col = lane&15, row = (lane>>4)*4 + reg  [m89/m91]
  const int rowb = m0 + wm * 128 + kg * 4;
  const int colb = n0 + wn * 64 + r16;
  if (MODE == 1) {
    const int e = (ecol_off + n0) >> 12;
#pragma unroll
    for (int m4 = 0; m4 < 8; ++m4) {
      int r0a = rowb + m4 * 16;
#pragma unroll
      for (int r = 0; r < 4; ++r) {
        int row = r0a + r;
        float gv = gate[(size_t)row * 4 + e];
#pragma unroll
        for (int n4 = 0; n4 < 4; ++n4) {
          int col = colb + n4 * 16;
          float v = acc[m4][n4][r] + bias[ecol_off + col];
          OutB[(size_t)row * ldc + col] = f2bf(fmaxf(v, 0.f) * gv);
        }
      }
    }
  } else {
#pragma unroll
    for (int m4 = 0; m4 < 8; ++m4) {
      int r0a = rowb + m4 * 16;
#pragma unroll
      for (int r = 0; r < 4; ++r) {
        int row = r0a + r;
#pragma unroll
        for (int n4 = 0; n4 < 4; ++n4) {
          int col = colb + n4 * 16;
          float bt = 0.f;
          for (int j = 0; j < eg; ++j)
            bt += gate[(size_t)row * 4 + e0 + j] * bias[(e0 + j) * 1024 + col];
          float v = acc[m4][n4][r] + bt;
          size_t oi = (size_t)row * ldc + col;
          if (accum) v += OutF[oi];
          OutF[oi] = v;
        }
      }
    }
  }
}

extern "C" void kernel_launch(void* const* d_in, const int* in_sizes, int n_in,
                              void* d_out, int out_size, void* d_ws, size_t ws_size,
                              hipStream_t stream) {
  const float* q  = (const float*)d_in[0];
  const float* k  = (const float*)d_in[1];
  const float* W1 = (const float*)d_in[2];
  const float* b1 = (const float*)d_in[3];
  const float* W2 = (const float*)d_in[4];
  const float* b2 = (const float*)d_in[5];
  const float* Wg = (const float*)d_in[6];
  const float* bg = (const float*)d_in[7];
  float* out = (float*)d_out;

  char* ws = (char*)d_ws;
  size_t off = 0;
  float* gate = (float*)(ws + off); off += (size_t)N_TOK * 4 * sizeof(float);
  short* qb   = (short*)(ws + off); off += (size_t)N_TOK * DIM * 2;
  short* W1t  = (short*)(ws + off); off += (size_t)NEXP * (size_t)DIM * HID * 2;   // [E*H][D]
  short* W2t2 = (short*)(ws + off); off += (size_t)NEXP * (size_t)HID * DIM * 2;   // [D][E*H]
  const size_t fixed = off;

  gate_kernel<<<dim3(N_TOK / 4), dim3(256), 0, stream>>>(q, k, Wg, bg, gate);
  convert_bf16_kernel<<<dim3(2048), dim3(256), 0, stream>>>(q, qb, N_TOK * DIM / 4);
  // W1 [E][D][H] -> W1t [E*H][D]
  transpose_bf16_kernel<<<dim3(HID / 64, DIM / 64, NEXP), dim3(256), 0, stream>>>(
      W1, W1t, DIM, HID, DIM, HID, 0);
  // W2 [E][H][D] -> W2t2 [D][E*H]
  transpose_bf16_kernel<<<dim3(DIM / 64, HID / 64, NEXP), dim3(256), 0, stream>>>(
      W2, W2t2, HID, DIM, NEXP * HID, 0, HID);

  size_t avail = (ws_size > fixed) ? ws_size - fixed : 0;

  if ((size_t)N_TOK * HID * 2 <= avail) {
    // full-M path; pick largest expert group that fits (eg in {4,2,1})
    int eg = 4;
    while (eg > 1 && (size_t)N_TOK * eg * HID * 2 > avail) eg >>= 1;
    short* Hs = (short*)(ws + fixed);  // [N_TOK][eg*H]
    const int ng = NEXP / eg;
    for (int gi = 0; gi < ng; ++gi) {
      int e0 = gi * eg;
      gemm256<1><<<dim3((N_TOK / 256) * (eg * HID / 256)), dim3(512), 0, stream>>>(
          qb, W1t + (size_t)e0 * HID * DIM, DIM, DIM, DIM, eg * HID / 256,
          b1, gate, e0 * HID, 0, 0, 0, Hs, nullptr, eg * HID);
      gemm256<2><<<dim3((N_TOK / 256) * (DIM / 256)), dim3(512), 0, stream>>>(
          Hs, W2t2 + (size_t)e0 * HID, eg * HID, eg * HID, NEXP * HID, DIM / 256,
          b2, gate, 0, e0, eg, gi > 0 ? 1 : 0, nullptr, out, DIM);
    }
  } else {
    // row-chunked per-expert fallback (tiny ws)
    short* Hs = (short*)(ws + fixed);
    long long mc = (long long)(avail / ((size_t)HID * 2));
    mc &= ~255LL;
    if (mc < 256) mc = 256;
    if (mc > N_TOK) mc = N_TOK;
    for (int cb = 0; cb < N_TOK; cb += (int)mc) {
      int rows = (N_TOK - cb < (int)mc) ? (N_TOK - cb) : (int)mc;
      int NTM = rows / 256;
      for (int e = 0; e < NEXP; ++e) {
        gemm256<1><<<dim3(NTM * (HID / 256)), dim3(512), 0, stream>>>(
            qb + (size_t)cb * DIM, W1t + (size_t)e * HID * DIM, DIM, DIM, DIM, HID / 256,
            b1, gate + (size_t)cb * 4, e * HID, 0, 0, 0, Hs, nullptr, HID);
        gemm256<2><<<dim3(NTM * (DIM / 256)), dim3(512), 0, stream>>>(
            Hs, W2t2 + (size_t)e * HID, HID, HID, NEXP * HID, DIM / 256,
            b2, gate + (size_t)cb * 4, 0, e, 1, (e > 0) ? 1 : 0, nullptr,
            out + (size_t)cb * DIM, DIM);
      }
    }
  }
}

// Round 5
// 1599.644 us; speedup vs baseline: 1.0697x; 1.0697x over previous
//
#include <hip/hip_runtime.h>
#include <hip/hip_bf16.h>

#define N_TOK 16384
#define DIM   1024
#define NEXP  4
#define HID   4096

typedef __attribute__((ext_vector_type(8))) short short8;
typedef __attribute__((ext_vector_type(4))) short short4v;
typedef __attribute__((ext_vector_type(4))) float float4v;

static __device__ __forceinline__ short f2bf(float f) {
  __hip_bfloat16 h = __float2bfloat16(f);
  return *reinterpret_cast<short*>(&h);
}

#define GLOAD_LDS16(gsrc, ldst)                                                            \
  __builtin_amdgcn_global_load_lds((const __attribute__((address_space(1))) void*)(gsrc),  \
                                   (__attribute__((address_space(3))) void*)(ldst), 16, 0, 0)

// ---------------- gate: softmax(concat(q,k) @ Wg + bg) ----------------
__global__ void gate_kernel(const float* __restrict__ q, const float* __restrict__ k,
                            const float* __restrict__ Wg, const float* __restrict__ bg,
                            float* __restrict__ gate) {
  const int wave = threadIdx.x >> 6, lane = threadIdx.x & 63;
  const int n = blockIdx.x * 4 + wave;
  const float* qr = q + (size_t)n * DIM;
  const float* kr = k + (size_t)n * DIM;
  float s0 = 0.f, s1 = 0.f, s2 = 0.f, s3 = 0.f;
  for (int i = 0; i < DIM / 64; ++i) {
    int d = i * 64 + lane;
    float x = qr[d];
    float4 w = *(const float4*)(Wg + (size_t)d * 4);
    s0 += x * w.x; s1 += x * w.y; s2 += x * w.z; s3 += x * w.w;
    float y = kr[d];
    float4 w2 = *(const float4*)(Wg + (size_t)(DIM + d) * 4);
    s0 += y * w2.x; s1 += y * w2.y; s2 += y * w2.z; s3 += y * w2.w;
  }
  for (int off = 32; off; off >>= 1) {
    s0 += __shfl_xor(s0, off);
    s1 += __shfl_xor(s1, off);
    s2 += __shfl_xor(s2, off);
    s3 += __shfl_xor(s3, off);
  }
  if (lane == 0) {
    float l0 = s0 + bg[0], l1 = s1 + bg[1], l2 = s2 + bg[2], l3 = s3 + bg[3];
    float m = fmaxf(fmaxf(l0, l1), fmaxf(l2, l3));
    float e0 = expf(l0 - m), e1 = expf(l1 - m), e2 = expf(l2 - m), e3 = expf(l3 - m);
    float inv = 1.f / (e0 + e1 + e2 + e3);
    float4 g; g.x = e0 * inv; g.y = e1 * inv; g.z = e2 * inv; g.w = e3 * inv;
    *(float4*)(gate + (size_t)n * 4) = g;
  }
}

// ---------------- f32 -> bf16 straight convert ----------------
__global__ void convert_bf16_kernel(const float* __restrict__ in, short* __restrict__ out, int n4) {
  int stride = gridDim.x * blockDim.x;
  for (int i = blockIdx.x * blockDim.x + threadIdx.x; i < n4; i += stride) {
    float4 v = *(const float4*)(in + (size_t)i * 4);
    short4v o;
    o[0] = f2bf(v.x); o[1] = f2bf(v.y); o[2] = f2bf(v.z); o[3] = f2bf(v.w);
    *(short4v*)(out + (size_t)i * 4) = o;
  }
}

// ---- LDS-tiled transpose+convert: in[z][R][C] f32 -> out[z*z_row + c][z*z_col + r] bf16 ----
__global__ void transpose_bf16_kernel(const float* __restrict__ in, short* __restrict__ out,
                                      int R, int C, int ldo, int z_row, int z_col) {
  __shared__ float tile[64][65];
  const int z = blockIdx.z;
  const float* src = in + (size_t)z * R * C;
  const int r0 = blockIdx.y * 64, c0 = blockIdx.x * 64;
  const int tc = threadIdx.x & 63, tr = threadIdx.x >> 6;
#pragma unroll
  for (int p = 0; p < 16; ++p) {
    int r = p * 4 + tr;
    tile[r][tc] = src[(size_t)(r0 + r) * C + (c0 + tc)];
  }
  __syncthreads();
#pragma unroll
  for (int p = 0; p < 16; ++p) {
    int i = p * 4 + tr;
    out[(size_t)(z * z_row + c0 + i) * ldo + z * z_col + (r0 + tc)] = f2bf(tile[tc][i]);
  }
}

// ============ 256x256 8-wave bf16 MFMA GEMM — race-free derived-waits pipeline =============
// LDS/operand: [buf 2][kh 2][256][32] shorts; swizzle chunk ^= (row>>1)&3; inverse on gsrc.
// Publication invariant: a slot is READ only after (all waves drained its staging via counted
// vmcnt) THEN a barrier; a slot is OVERWRITTEN only >=1 phase after its last reader's counted
// lgkm drain (i.e. after that phase-end barrier).
// Phase layout (tile t): P0=(k0,m0) P1=(k0,m1) P2=(k1,m0) P3=(k1,m1); reads issued 1 phase
// ahead into alternating reg sets; lgkm waits {4,8,4,8} (never 0 mid-loop).
// Stage stagger: P0:A(t+1)k1  P1:B(t+2)k0  P2:A(t+2)k0  P3:B(t+2)k1.
// vmcnt after MFMA, BEFORE phase-end barrier:
//   P0: 8*[t+1<T]  (drains tile-t k1 -> P1/P2 reads safe after P0-end barrier)
//   P2: 4*[t+1<T]+4*[t+2<T]  (drains tile-t+1 k0 -> P3 reads safe after P2-end barrier)
template <int MODE>
__global__ __launch_bounds__(512, 2)
void gemm256(const short* __restrict__ A, const short* __restrict__ Bt,
             int K, int lda, int ldb, int NTN,
             const float* __restrict__ bias, const float* __restrict__ gate,
             int ecol_off, int e0, int eg, int accum,
             short* __restrict__ OutB, float* __restrict__ OutF, int ldc) {
  __shared__ short sA[32768];
  __shared__ short sB[32768];

  const int nwg = gridDim.x;
  const int NTM = nwg / NTN;
  int bid = blockIdx.x;
  int qd = nwg >> 3, rm = nwg & 7;
  int xcd = bid & 7, idx = bid >> 3;
  int swz = (xcd < rm ? xcd * (qd + 1) : rm * (qd + 1) + (xcd - rm) * qd) + idx;
  const int tpg = 8 * NTN;
  int g = swz / tpg;
  int lg = swz % tpg;
  int gm0 = g * 8;
  int gsz = NTM - gm0; if (gsz > 8) gsz = 8;
  const int tile_m = gm0 + lg % gsz;
  const int tile_n = lg / gsz;
  const int m0 = tile_m * 256;
  const int n0 = tile_n * 256;

  const int tid = threadIdx.x;
  const int lane = tid & 63;
  const int wid = tid >> 6;
  const int wm = wid >> 2, wn = wid & 3;
  const int r16 = lane & 15, kg = lane >> 4;
  const int swc8 = ((kg ^ ((r16 >> 1) & 3)) << 3);
  const int aRow = (wm * 128 + r16) * 32 + swc8;  // +2048 for m-half 1
  const int bRow = (wn * 64 + r16) * 32 + swc8;
  const int rowStage = tid >> 2;
  const int cg8 = (((tid & 3) ^ ((tid >> 3) & 3)) << 3);
  const int st8 = tid * 8;

  const short* aStage = A + (size_t)(m0 + rowStage) * lda + cg8;
  const short* bStage = Bt + (size_t)(n0 + rowStage) * ldb + cg8;

#define STG_A(t, kh)                                              \
  do {                                                            \
    const short* g_ = aStage + (t) * 64 + (kh) * 32;              \
    int l_ = ((((t) & 1) << 14) | ((kh) << 13)) + st8;            \
    GLOAD_LDS16(g_, sA + l_);                                     \
    GLOAD_LDS16(g_ + (size_t)128 * lda, sA + l_ + 4096);          \
  } while (0)
#define STG_B(t, kh)                                              \
  do {                                                            \
    const short* g_ = bStage + (t) * 64 + (kh) * 32;              \
    int l_ = ((((t) & 1) << 14) | ((kh) << 13)) + st8;            \
    GLOAD_LDS16(g_, sB + l_);                                     \
    GLOAD_LDS16(g_ + (size_t)128 * ldb, sB + l_ + 4096);          \
  } while (0)

  float4v acc[8][4];
#pragma unroll
  for (int m = 0; m < 8; ++m)
#pragma unroll
    for (int n = 0; n < 4; ++n) acc[m][n] = (float4v)0.0f;

  short8 aS0[4], aS1[4], bk0[4], bk1[4];
  const int T = K >> 6;

  // prologue: B0k0 A0k0 B0k1 A0k1 [B1k0 A1k0 B1k1]; A1k1 left for t0-P0.
  STG_B(0, 0); STG_A(0, 0); STG_B(0, 1); STG_A(0, 1);
  if (T > 1) { STG_B(1, 0); STG_A(1, 0); STG_B(1, 1); }
  if (T > 1) asm volatile("s_waitcnt vmcnt(10)" ::: "memory");  // drain B0k0,A0k0
  else       asm volatile("s_waitcnt vmcnt(4)" ::: "memory");
  __builtin_amdgcn_sched_barrier(0);
  __builtin_amdgcn_s_barrier();
  // pre-loop reads for P0(0): A(m0,k0), B(k0) from buf0 kh0
#pragma unroll
  for (int i = 0; i < 4; ++i) aS0[i] = *(const short8*)(sA + aRow + i * 512);
#pragma unroll
  for (int n = 0; n < 4; ++n) bk0[n] = *(const short8*)(sB + bRow + n * 512);

  for (int t = 0; t < T; ++t) {
    const int c = (t & 1) << 14;
    const int o = ((t + 1) & 1) << 14;
    const bool s2 = (t + 2 < T), s1 = (t + 1 < T);
    // -------- P0: stage A(t+1)k1; read A(m1,k0); MFMA(k0,m0); vmcnt publishes tile-t k1
    if (s1) STG_A(t + 1, 1);
#pragma unroll
    for (int i = 0; i < 4; ++i) aS1[i] = *(const short8*)(sA + c + 2048 + aRow + i * 512);
    __builtin_amdgcn_s_barrier();
    asm volatile("s_waitcnt lgkmcnt(4)" ::: "memory");
    __builtin_amdgcn_sched_barrier(0);
    __builtin_amdgcn_s_setprio(1);
#pragma unroll
    for (int i = 0; i < 4; ++i)
#pragma unroll
      for (int n = 0; n < 4; ++n)
        acc[i][n] = __builtin_amdgcn_mfma_f32_16x16x32_bf16(aS0[i], bk0[n], acc[i][n], 0, 0, 0);
    __builtin_amdgcn_s_setprio(0);
    if (s1) asm volatile("s_waitcnt vmcnt(8)" ::: "memory");
    else    asm volatile("s_waitcnt vmcnt(0)" ::: "memory");
    __builtin_amdgcn_sched_barrier(0);
    __builtin_amdgcn_s_barrier();
    // -------- P1: stage B(t+2)k0; read A(m0,k1)+B(k1); MFMA(k0,m1)
    if (s2) STG_B(t + 2, 0);
#pragma unroll
    for (int i = 0; i < 4; ++i) aS0[i] = *(const short8*)(sA + c + 8192 + aRow + i * 512);
#pragma unroll
    for (int n = 0; n < 4; ++n) bk1[n] = *(const short8*)(sB + c + 8192 + bRow + n * 512);
    __builtin_amdgcn_s_barrier();
    asm volatile("s_waitcnt lgkmcnt(8)" ::: "memory");
    __builtin_amdgcn_sched_barrier(0);
    __builtin_amdgcn_s_setprio(1);
#pragma unroll
    for (int i = 0; i < 4; ++i)
#pragma unroll
      for (int n = 0; n < 4; ++n)
        acc[4 + i][n] = __builtin_amdgcn_mfma_f32_16x16x32_bf16(aS1[i], bk0[n], acc[4 + i][n], 0, 0, 0);
    __builtin_amdgcn_s_setprio(0);
    __builtin_amdgcn_sched_barrier(0);
    __builtin_amdgcn_s_barrier();
    // -------- P2: stage A(t+2)k0; read A(m1,k1); MFMA(k1,m0); vmcnt publishes tile-t+1 k0
    if (s2) STG_A(t + 2, 0);
#pragma unroll
    for (int i = 0; i < 4; ++i) aS1[i] = *(const short8*)(sA + c + 8192 + 2048 + aRow + i * 512);
    __builtin_amdgcn_s_barrier();
    asm volatile("s_waitcnt lgkmcnt(4)" ::: "memory");
    __builtin_amdgcn_sched_barrier(0);
    __builtin_amdgcn_s_setprio(1);
#pragma unroll
    for (int i = 0; i < 4; ++i)
#pragma unroll
      for (int n = 0; n < 4; ++n)
        acc[i][n] = __builtin_amdgcn_mfma_f32_16x16x32_bf16(aS0[i], bk1[n], acc[i][n], 0, 0, 0);
    __builtin_amdgcn_s_setprio(0);
    if (s2)      asm volatile("s_waitcnt vmcnt(8)" ::: "memory");
    else if (s1) asm volatile("s_waitcnt vmcnt(4)" ::: "memory");
    else         asm volatile("s_waitcnt vmcnt(0)" ::: "memory");
    __builtin_amdgcn_sched_barrier(0);
    __builtin_amdgcn_s_barrier();
    // -------- P3: stage B(t+2)k1; read next-tile kh0 (buf o); MFMA(k1,m1)
    if (s2) STG_B(t + 2, 1);
    if (s1) {
#pragma unroll
      for (int i = 0; i < 4; ++i) aS0[i] = *(const short8*)(sA + o + aRow + i * 512);
#pragma unroll
      for (int n = 0; n < 4; ++n) bk0[n] = *(const short8*)(sB + o + bRow + n * 512);
    }
    __builtin_amdgcn_s_barrier();
    if (s1) asm volatile("s_waitcnt lgkmcnt(8)" ::: "memory");
    else    asm volatile("s_waitcnt lgkmcnt(0)" ::: "memory");
    __builtin_amdgcn_sched_barrier(0);
    __builtin_amdgcn_s_setprio(1);
#pragma unroll
    for (int i = 0; i < 4; ++i)
#pragma unroll
      for (int n = 0; n < 4; ++n)
        acc[4 + i][n] = __builtin_amdgcn_mfma_f32_16x16x32_bf16(aS1[i], bk1[n], acc[4 + i][n], 0, 0, 0);
    __builtin_amdgcn_s_setprio(0);
    __builtin_amdgcn_sched_barrier(0);
    __builtin_amdgcn_s_barrier();
  }
#undef STG_A
#undef STG_B

  // epilogue: C/D layout col = lane&15, row = (lane>>4)*4 + reg  [m89/m91]
  const int rowb = m0 + wm * 128 + kg * 4;
  const int colb = n0 + wn * 64 + r16;
  if (MODE == 1) {
    const int e = (ecol_off + n0) >> 12;
#pragma unroll
    for (int m4 = 0; m4 < 8; ++m4) {
      int r0a = rowb + m4 * 16;
#pragma unroll
      for (int r = 0; r < 4; ++r) {
        int row = r0a + r;
        float gv = gate[(size_t)row * 4 + e];
#pragma unroll
        for (int n4 = 0; n4 < 4; ++n4) {
          int col = colb + n4 * 16;
          float v = acc[m4][n4][r] + bias[ecol_off + col];
          OutB[(size_t)row * ldc + col] = f2bf(fmaxf(v, 0.f) * gv);
        }
      }
    }
  } else {
#pragma unroll
    for (int m4 = 0; m4 < 8; ++m4) {
      int r0a = rowb + m4 * 16;
#pragma unroll
      for (int r = 0; r < 4; ++r) {
        int row = r0a + r;
#pragma unroll
        for (int n4 = 0; n4 < 4; ++n4) {
          int col = colb + n4 * 16;
          float bt = 0.f;
          for (int j = 0; j < eg; ++j)
            bt += gate[(size_t)row * 4 + e0 + j] * bias[(e0 + j) * 1024 + col];
          float v = acc[m4][n4][r] + bt;
          size_t oi = (size_t)row * ldc + col;
          if (accum) v += OutF[oi];
          OutF[oi] = v;
        }
      }
    }
  }
}

extern "C" void kernel_launch(void* const* d_in, const int* in_sizes, int n_in,
                              void* d_out, int out_size, void* d_ws, size_t ws_size,
                              hipStream_t stream) {
  const float* q  = (const float*)d_in[0];
  const float* k  = (const float*)d_in[1];
  const float* W1 = (const float*)d_in[2];
  const float* b1 = (const float*)d_in[3];
  const float* W2 = (const float*)d_in[4];
  const float* b2 = (const float*)d_in[5];
  const float* Wg = (const float*)d_in[6];
  const float* bg = (const float*)d_in[7];
  float* out = (float*)d_out;

  char* ws = (char*)d_ws;
  size_t off = 0;
  float* gate = (float*)(ws + off); off += (size_t)N_TOK * 4 * sizeof(float);
  short* qb   = (short*)(ws + off); off += (size_t)N_TOK * DIM * 2;
  short* W1t  = (short*)(ws + off); off += (size_t)NEXP * (size_t)DIM * HID * 2;   // [E*H][D]
  short* W2t2 = (short*)(ws + off); off += (size_t)NEXP * (size_t)HID * DIM * 2;   // [D][E*H]
  const size_t fixed = off;

  gate_kernel<<<dim3(N_TOK / 4), dim3(256), 0, stream>>>(q, k, Wg, bg, gate);
  convert_bf16_kernel<<<dim3(2048), dim3(256), 0, stream>>>(q, qb, N_TOK * DIM / 4);
  transpose_bf16_kernel<<<dim3(HID / 64, DIM / 64, NEXP), dim3(256), 0, stream>>>(
      W1, W1t, DIM, HID, DIM, HID, 0);
  transpose_bf16_kernel<<<dim3(DIM / 64, HID / 64, NEXP), dim3(256), 0, stream>>>(
      W2, W2t2, HID, DIM, NEXP * HID, 0, HID);

  size_t avail = (ws_size > fixed) ? ws_size - fixed : 0;

  if ((size_t)N_TOK * HID * 2 <= avail) {
    int eg = 4;
    while (eg > 1 && (size_t)N_TOK * eg * HID * 2 > avail) eg >>= 1;
    short* Hs = (short*)(ws + fixed);
    const int ng = NEXP / eg;
    for (int gi = 0; gi < ng; ++gi) {
      int e0 = gi * eg;
      gemm256<1><<<dim3((N_TOK / 256) * (eg * HID / 256)), dim3(512), 0, stream>>>(
          qb, W1t + (size_t)e0 * HID * DIM, DIM, DIM, DIM, eg * HID / 256,
          b1, gate, e0 * HID, 0, 0, 0, Hs, nullptr, eg * HID);
      gemm256<2><<<dim3((N_TOK / 256) * (DIM / 256)), dim3(512), 0, stream>>>(
          Hs, W2t2 + (size_t)e0 * HID, eg * HID, eg * HID, NEXP * HID, DIM / 256,
          b2, gate, 0, e0, eg, gi > 0 ? 1 : 0, nullptr, out, DIM);
    }
  } else {
    short* Hs = (short*)(ws + fixed);
    long long mc = (long long)(avail / ((size_t)HID * 2));
    mc &= ~255LL;
    if (mc < 256) mc = 256;
    if (mc > N_TOK) mc = N_TOK;
    for (int cb = 0; cb < N_TOK; cb += (int)mc) {
      int rows = (N_TOK - cb < (int)mc) ? (N_TOK - cb) : (int)mc;
      int NTM = rows / 256;
      for (int e = 0; e < NEXP; ++e) {
        gemm256<1><<<dim3(NTM * (HID / 256)), dim3(512), 0, stream>>>(
            qb + (size_t)cb * DIM, W1t + (size_t)e * HID * DIM, DIM, DIM, DIM, HID / 256,
            b1, gate + (size_t)cb * 4, e * HID, 0, 0, 0, Hs, nullptr, HID);
        gemm256<2><<<dim3(NTM * (DIM / 256)), dim3(512), 0, stream>>>(
            Hs, W2t2 + (size_t)e * HID, HID, HID, NEXP * HID, DIM / 256,
            b2, gate + (size_t)cb * 4, 0, e, 1, (e > 0) ? 1 : 0, nullptr,
            out + (size_t)cb * DIM, DIM);
      }
    }
  }
}

// Round 6
// 1502.951 us; speedup vs baseline: 1.1385x; 1.0643x over previous
//
#include <hip/hip_runtime.h>
#include <hip/hip_bf16.h>

#define N_TOK 16384
#define DIM   1024
#define NEXP  4
#define HID   4096

typedef __attribute__((ext_vector_type(8))) short short8;
typedef __attribute__((ext_vector_type(4))) short short4v;
typedef __attribute__((ext_vector_type(16))) float f32x16;

static __device__ __forceinline__ short f2bf(float f) {
  __hip_bfloat16 h = __float2bfloat16(f);
  return *reinterpret_cast<short*>(&h);
}

#define GLOAD_LDS16(gsrc, ldst)                                                            \
  __builtin_amdgcn_global_load_lds((const __attribute__((address_space(1))) void*)(gsrc),  \
                                   (__attribute__((address_space(3))) void*)(ldst), 16, 0, 0)

// ---------------- gate: softmax(concat(q,k) @ Wg + bg) ----------------
__global__ void gate_kernel(const float* __restrict__ q, const float* __restrict__ k,
                            const float* __restrict__ Wg, const float* __restrict__ bg,
                            float* __restrict__ gate) {
  const int wave = threadIdx.x >> 6, lane = threadIdx.x & 63;
  const int n = blockIdx.x * 4 + wave;
  const float* qr = q + (size_t)n * DIM;
  const float* kr = k + (size_t)n * DIM;
  float s0 = 0.f, s1 = 0.f, s2 = 0.f, s3 = 0.f;
  for (int i = 0; i < DIM / 64; ++i) {
    int d = i * 64 + lane;
    float x = qr[d];
    float4 w = *(const float4*)(Wg + (size_t)d * 4);
    s0 += x * w.x; s1 += x * w.y; s2 += x * w.z; s3 += x * w.w;
    float y = kr[d];
    float4 w2 = *(const float4*)(Wg + (size_t)(DIM + d) * 4);
    s0 += y * w2.x; s1 += y * w2.y; s2 += y * w2.z; s3 += y * w2.w;
  }
  for (int off = 32; off; off >>= 1) {
    s0 += __shfl_xor(s0, off);
    s1 += __shfl_xor(s1, off);
    s2 += __shfl_xor(s2, off);
    s3 += __shfl_xor(s3, off);
  }
  if (lane == 0) {
    float l0 = s0 + bg[0], l1 = s1 + bg[1], l2 = s2 + bg[2], l3 = s3 + bg[3];
    float m = fmaxf(fmaxf(l0, l1), fmaxf(l2, l3));
    float e0 = expf(l0 - m), e1 = expf(l1 - m), e2 = expf(l2 - m), e3 = expf(l3 - m);
    float inv = 1.f / (e0 + e1 + e2 + e3);
    float4 g; g.x = e0 * inv; g.y = e1 * inv; g.z = e2 * inv; g.w = e3 * inv;
    *(float4*)(gate + (size_t)n * 4) = g;
  }
}

// ---------------- f32 -> bf16 straight convert ----------------
__global__ void convert_bf16_kernel(const float* __restrict__ in, short* __restrict__ out, int n4) {
  int stride = gridDim.x * blockDim.x;
  for (int i = blockIdx.x * blockDim.x + threadIdx.x; i < n4; i += stride) {
    float4 v = *(const float4*)(in + (size_t)i * 4);
    short4v o;
    o[0] = f2bf(v.x); o[1] = f2bf(v.y); o[2] = f2bf(v.z); o[3] = f2bf(v.w);
    *(short4v*)(out + (size_t)i * 4) = o;
  }
}

// ---- LDS-tiled transpose+convert: in[z][R][C] f32 -> out[z*z_row + c][z*z_col + r] bf16 ----
__global__ void transpose_bf16_kernel(const float* __restrict__ in, short* __restrict__ out,
                                      int R, int C, int ldo, int z_row, int z_col) {
  __shared__ float tile[64][65];
  const int z = blockIdx.z;
  const float* src = in + (size_t)z * R * C;
  const int r0 = blockIdx.y * 64, c0 = blockIdx.x * 64;
  const int tc = threadIdx.x & 63, tr = threadIdx.x >> 6;
#pragma unroll
  for (int p = 0; p < 16; ++p) {
    int r = p * 4 + tr;
    tile[r][tc] = src[(size_t)(r0 + r) * C + (c0 + tc)];
  }
  __syncthreads();
#pragma unroll
  for (int p = 0; p < 16; ++p) {
    int i = p * 4 + tr;
    out[(size_t)(z * z_row + c0 + i) * ldo + z * z_col + (r0 + tc)] = f2bf(tile[tc][i]);
  }
}

// ========== bf16 MFMA GEMM: C = A[M,K] @ Bt[N,K]^T, 128x128 tile, BK=64, 32x32x16 ==========
// R1-proven structure (2-barrier, global_load_lds staging, chunk^=(row&7) swizzle, 0 conflicts)
// with 32x32x16 fragments: per wave 2x2 frags of 32x32 -> 16 MFMA + 16 ds_read_b128 per K-tile.
// A/B operand: row = lane&31, k = (lane>>5)*8 + j  (32-lane extension of verified 16x16 map).
// C/D layout [m74/m101]: col = lane&31, row = (reg&3) + 8*(reg>>2) + 4*(lane>>5).
// MODE 1: OutB[row,col] = bf16( gate[row,e] * relu(C + bias[col]) )
// MODE 2: OutF[row,col] (+)= C + gate[row,e]*bias[col]
template <int MODE>
__global__ __launch_bounds__(256, 4)
void gemm_kernel(const short* __restrict__ A, const short* __restrict__ Bt,
                 int K, int lda, int ldb,
                 const float* __restrict__ bias, const float* __restrict__ gate, int e,
                 short* __restrict__ OutB, float* __restrict__ FOut, int ldc, int accumulate) {
  __shared__ short sA[128 * 64];
  __shared__ short sB[128 * 64];
  const int t = threadIdx.x;
  const int m0 = blockIdx.y * 128;
  const int n0 = blockIdx.x * 128;
  const int lane = t & 63;
  const int wave = t >> 6;
  const int wm = (wave >> 1) * 64;
  const int wn = (wave & 1) * 64;
  const int r32 = lane & 31;
  const int kh2 = lane >> 5;

  f32x16 acc[2][2];
#pragma unroll
  for (int m = 0; m < 2; ++m)
#pragma unroll
    for (int n = 0; n < 2; ++n) acc[m][n] = (f32x16)0.0f;

  for (int k0 = 0; k0 < K; k0 += 64) {
    // stage A/B tiles: linear LDS dest, inverse-swizzled global source (rule #21)
#pragma unroll
    for (int i = 0; i < 4; ++i) {
      int c = i * 256 + t;
      int row = c >> 3;
      int jc = (c & 7) ^ (row & 7);
      GLOAD_LDS16(A + (size_t)(m0 + row) * lda + k0 + jc * 8, &sA[c * 8]);
      GLOAD_LDS16(Bt + (size_t)(n0 + row) * ldb + k0 + jc * 8, &sB[c * 8]);
    }
    __syncthreads();  // drains vmcnt: staged data visible
#pragma unroll
    for (int ks = 0; ks < 4; ++ks) {
      short8 af[2], bfr[2];
#pragma unroll
      for (int m = 0; m < 2; ++m) {
        int row = wm + m * 32 + r32;
        int jc = (ks * 2 + kh2) ^ (row & 7);
        af[m] = *(const short8*)&sA[row * 64 + jc * 8];
      }
#pragma unroll
      for (int n = 0; n < 2; ++n) {
        int row = wn + n * 32 + r32;
        int jc = (ks * 2 + kh2) ^ (row & 7);
        bfr[n] = *(const short8*)&sB[row * 64 + jc * 8];
      }
#pragma unroll
      for (int m = 0; m < 2; ++m)
#pragma unroll
        for (int n = 0; n < 2; ++n)
          acc[m][n] = __builtin_amdgcn_mfma_f32_32x32x16_bf16(af[m], bfr[n], acc[m][n], 0, 0, 0);
    }
    __syncthreads();  // all ds_reads done before next stage overwrites
  }

  // epilogue: col = lane&31, row = (reg&3) + 8*(reg>>2) + 4*(lane>>5)
#pragma unroll
  for (int m = 0; m < 2; ++m) {
    int rbase = m0 + wm + m * 32 + 4 * kh2;
#pragma unroll
    for (int n = 0; n < 2; ++n) {
      int col = n0 + wn + n * 32 + r32;
      float bcol = bias[col];
#pragma unroll
      for (int r = 0; r < 16; ++r) {
        int grow = rbase + (r & 3) + 8 * (r >> 2);
        float g = gate[(size_t)grow * 4 + e];
        float v = acc[m][n][r];
        if (MODE == 1) {
          v += bcol;
          v = fmaxf(v, 0.f);
          v *= g;
          OutB[(size_t)grow * ldc + col] = f2bf(v);
        } else {
          v += g * bcol;
          size_t oi = (size_t)grow * ldc + col;
          if (accumulate) v += FOut[oi];
          FOut[oi] = v;
        }
      }
    }
  }
}

extern "C" void kernel_launch(void* const* d_in, const int* in_sizes, int n_in,
                              void* d_out, int out_size, void* d_ws, size_t ws_size,
                              hipStream_t stream) {
  const float* q  = (const float*)d_in[0];
  const float* k  = (const float*)d_in[1];
  const float* W1 = (const float*)d_in[2];
  const float* b1 = (const float*)d_in[3];
  const float* W2 = (const float*)d_in[4];
  const float* b2 = (const float*)d_in[5];
  const float* Wg = (const float*)d_in[6];
  const float* bg = (const float*)d_in[7];
  float* out = (float*)d_out;

  char* ws = (char*)d_ws;
  size_t off = 0;
  float* gate = (float*)(ws + off); off += (size_t)N_TOK * 4 * sizeof(float);
  short* qb   = (short*)(ws + off); off += (size_t)N_TOK * DIM * 2;
  short* W1t  = (short*)(ws + off); off += (size_t)NEXP * (size_t)DIM * HID * 2;   // [E*H][D]
  short* W2t2 = (short*)(ws + off); off += (size_t)NEXP * (size_t)HID * DIM * 2;   // [D][E*H]
  const size_t fixed = off;

  gate_kernel<<<dim3(N_TOK / 4), dim3(256), 0, stream>>>(q, k, Wg, bg, gate);
  convert_bf16_kernel<<<dim3(2048), dim3(256), 0, stream>>>(q, qb, N_TOK * DIM / 4);
  // W1 [E][D][H] -> W1t [E*H][D]
  transpose_bf16_kernel<<<dim3(HID / 64, DIM / 64, NEXP), dim3(256), 0, stream>>>(
      W1, W1t, DIM, HID, DIM, HID, 0);
  // W2 [E][H][D] -> W2t2 [D][E*H]
  transpose_bf16_kernel<<<dim3(DIM / 64, HID / 64, NEXP), dim3(256), 0, stream>>>(
      W2, W2t2, HID, DIM, NEXP * HID, 0, HID);

  size_t avail = (ws_size > fixed) ? ws_size - fixed : 0;

  if ((size_t)N_TOK * HID * 2 <= avail) {
    // full-M per-expert (Hs = [N_TOK][HID] reused across experts)
    short* Hs = (short*)(ws + fixed);
    for (int e = 0; e < NEXP; ++e) {
      gemm_kernel<1><<<dim3(HID / 128, N_TOK / 128), dim3(256), 0, stream>>>(
          qb, W1t + (size_t)e * HID * DIM, DIM, DIM, DIM,
          b1 + (size_t)e * HID, gate, e, Hs, nullptr, HID, 0);
      gemm_kernel<2><<<dim3(DIM / 128, N_TOK / 128), dim3(256), 0, stream>>>(
          Hs, W2t2 + (size_t)e * HID, HID, HID, NEXP * HID,
          b2 + (size_t)e * DIM, gate, e, nullptr, out, DIM, e > 0);
    }
  } else {
    // row-chunked per-expert fallback (tiny ws)
    short* Hs = (short*)(ws + fixed);
    long long mc = (long long)(avail / ((size_t)HID * 2));
    mc &= ~127LL;
    if (mc < 128) mc = 128;
    if (mc > N_TOK) mc = N_TOK;
    for (int cb = 0; cb < N_TOK; cb += (int)mc) {
      int rows = (N_TOK - cb < (int)mc) ? (N_TOK - cb) : (int)mc;
      for (int e = 0; e < NEXP; ++e) {
        gemm_kernel<1><<<dim3(HID / 128, rows / 128), dim3(256), 0, stream>>>(
            qb + (size_t)cb * DIM, W1t + (size_t)e * HID * DIM, DIM, DIM, DIM,
            b1 + (size_t)e * HID, gate + (size_t)cb * 4, e, Hs, nullptr, HID, 0);
        gemm_kernel<2><<<dim3(DIM / 128, rows / 128), dim3(256), 0, stream>>>(
            Hs, W2t2 + (size_t)e * HID, HID, HID, NEXP * HID,
            b2 + (size_t)e * DIM, gate + (size_t)cb * 4, e, nullptr,
            out + (size_t)cb * DIM, DIM, e > 0);
      }
    }
  }
}

// Round 7
// 1281.897 us; speedup vs baseline: 1.3348x; 1.1724x over previous
//
#include <hip/hip_runtime.h>
#include <hip/hip_bf16.h>

#define N_TOK 16384
#define DIM   1024
#define NEXP  4
#define HID   4096

typedef __attribute__((ext_vector_type(8))) short short8;
typedef __attribute__((ext_vector_type(4))) short short4v;
typedef __attribute__((ext_vector_type(4))) float float4v;

static __device__ __forceinline__ short f2bf(float f) {
  __hip_bfloat16 h = __float2bfloat16(f);
  return *reinterpret_cast<short*>(&h);
}

#define GLOAD_LDS16(gsrc, ldst)                                                            \
  __builtin_amdgcn_global_load_lds((const __attribute__((address_space(1))) void*)(gsrc),  \
                                   (__attribute__((address_space(3))) void*)(ldst), 16, 0, 0)

// ---------------- gate: softmax(concat(q,k) @ Wg + bg) ----------------
__global__ void gate_kernel(const float* __restrict__ q, const float* __restrict__ k,
                            const float* __restrict__ Wg, const float* __restrict__ bg,
                            float* __restrict__ gate) {
  const int wave = threadIdx.x >> 6, lane = threadIdx.x & 63;
  const int n = blockIdx.x * 4 + wave;
  const float* qr = q + (size_t)n * DIM;
  const float* kr = k + (size_t)n * DIM;
  float s0 = 0.f, s1 = 0.f, s2 = 0.f, s3 = 0.f;
  for (int i = 0; i < DIM / 64; ++i) {
    int d = i * 64 + lane;
    float x = qr[d];
    float4 w = *(const float4*)(Wg + (size_t)d * 4);
    s0 += x * w.x; s1 += x * w.y; s2 += x * w.z; s3 += x * w.w;
    float y = kr[d];
    float4 w2 = *(const float4*)(Wg + (size_t)(DIM + d) * 4);
    s0 += y * w2.x; s1 += y * w2.y; s2 += y * w2.z; s3 += y * w2.w;
  }
  for (int off = 32; off; off >>= 1) {
    s0 += __shfl_xor(s0, off);
    s1 += __shfl_xor(s1, off);
    s2 += __shfl_xor(s2, off);
    s3 += __shfl_xor(s3, off);
  }
  if (lane == 0) {
    float l0 = s0 + bg[0], l1 = s1 + bg[1], l2 = s2 + bg[2], l3 = s3 + bg[3];
    float m = fmaxf(fmaxf(l0, l1), fmaxf(l2, l3));
    float e0 = expf(l0 - m), e1 = expf(l1 - m), e2 = expf(l2 - m), e3 = expf(l3 - m);
    float inv = 1.f / (e0 + e1 + e2 + e3);
    float4 g; g.x = e0 * inv; g.y = e1 * inv; g.z = e2 * inv; g.w = e3 * inv;
    *(float4*)(gate + (size_t)n * 4) = g;
  }
}

// ---------------- f32 -> bf16 straight convert ----------------
__global__ void convert_bf16_kernel(const float* __restrict__ in, short* __restrict__ out, int n4) {
  int stride = gridDim.x * blockDim.x;
  for (int i = blockIdx.x * blockDim.x + threadIdx.x; i < n4; i += stride) {
    float4 v = *(const float4*)(in + (size_t)i * 4);
    short4v o;
    o[0] = f2bf(v.x); o[1] = f2bf(v.y); o[2] = f2bf(v.z); o[3] = f2bf(v.w);
    *(short4v*)(out + (size_t)i * 4) = o;
  }
}

// ---- LDS-tiled transpose+convert: in[z][R][C] f32 -> out[z][C][R] bf16 (per-z contiguous) ----
__global__ void transpose_bf16_kernel(const float* __restrict__ in, short* __restrict__ out,
                                      int R, int C) {
  __shared__ float tile[64][65];
  const size_t eoff = (size_t)blockIdx.z * (size_t)R * C;
  const float* src = in + eoff;
  short* dst = out + eoff;
  const int r0 = blockIdx.y * 64, c0 = blockIdx.x * 64;
  const int tc = threadIdx.x & 63, tr = threadIdx.x >> 6;
#pragma unroll
  for (int p = 0; p < 16; ++p) {
    int r = p * 4 + tr;
    tile[r][tc] = src[(size_t)(r0 + r) * C + (c0 + tc)];
  }
  __syncthreads();
#pragma unroll
  for (int p = 0; p < 16; ++p) {
    int i = p * 4 + tr;
    dst[(size_t)(c0 + i) * R + (r0 + tc)] = f2bf(tile[tc][i]);
  }
}

// ---------------- bf16 MFMA GEMM: C = A[M,K] @ Bt[N,K]^T, 128x128 tile, BK=64 ----------------
// R1-proven kernel (16x16x32 frags, 2-barrier, global_load_lds, chunk^=(row&7) swizzle,
// 0 bank conflicts) + XCD-locality tile scheduling:
//   1-D grid; xcd = bid&7 (round-robin heuristic; bijective regardless).
//   M partitioned across XCDs (m_own = NTM/8 tiles -> A-panel ~4 MB, L2-resident).
//   Inner order: 8m x 4n windows (32 CUs share ~2MB A + ~1MB B), n-chunks swept, mg2 outer.
// MODE 1: OutB[row,col] = bf16( gate4[row*4] * relu(C + bias[col]) )
// MODE 2: FOut[row,col] (+)= C + gate4[row*4]*bias[col]
template <int MODE>
__global__ __launch_bounds__(256, 2)
void gemm_kernel(const short* __restrict__ A, const short* __restrict__ Bt, int K, int NTN,
                 const float* __restrict__ bias, const float* __restrict__ gate4,
                 short* __restrict__ OutB, float* __restrict__ FOut, int ldc, int accumulate) {
  const int nwg = gridDim.x;
  const int NTM = nwg / NTN;
  int tile_m, tile_n;
  if ((NTM & 7) == 0 && (NTN & 3) == 0) {
    const int m_own = NTM >> 3;
    const int xcd = blockIdx.x & 7;
    const int idx = blockIdx.x >> 3;
    const int mgrp = (m_own < 8) ? m_own : 8;
    const int per = mgrp * 4;
    const int pos = idx % per;
    const int chunk = idx / per;
    const int ml = pos % mgrp;
    const int nl = pos / mgrp;
    const int nchunks = NTN >> 2;
    const int nc = chunk % nchunks;
    const int mg2 = chunk / nchunks;
    tile_m = xcd * m_own + mg2 * mgrp + ml;
    tile_n = nc * 4 + nl;
  } else {
    tile_m = blockIdx.x / NTN;
    tile_n = blockIdx.x % NTN;
  }
  const int m0 = tile_m * 128;
  const int n0 = tile_n * 128;

  __shared__ short sA[128 * 64];
  __shared__ short sB[128 * 64];
  const int t = threadIdx.x;
  const int lane = t & 63;
  const int wave = t >> 6;
  const int wm = (wave >> 1) * 64;
  const int wn = (wave & 1) * 64;
  const int r16 = lane & 15;
  const int kg = lane >> 4;

  float4v acc[4][4];
#pragma unroll
  for (int m = 0; m < 4; ++m)
#pragma unroll
    for (int n = 0; n < 4; ++n) acc[m][n] = (float4v)0.0f;

  for (int k0 = 0; k0 < K; k0 += 64) {
    // stage A/B tiles: linear LDS dest, inverse-swizzled global source (rule #21)
#pragma unroll
    for (int i = 0; i < 4; ++i) {
      int c = i * 256 + t;
      int row = c >> 3;
      int jc = (c & 7) ^ (row & 7);
      GLOAD_LDS16(A + (size_t)(m0 + row) * K + k0 + jc * 8, &sA[c * 8]);
      GLOAD_LDS16(Bt + (size_t)(n0 + row) * K + k0 + jc * 8, &sB[c * 8]);
    }
    __syncthreads();  // drains vmcnt: staged data visible
#pragma unroll
    for (int kk = 0; kk < 2; ++kk) {
      short8 af[4], bfr[4];
#pragma unroll
      for (int m = 0; m < 4; ++m) {
        int row = wm + m * 16 + r16;
        int jc = (kk * 4 + kg) ^ (row & 7);
        af[m] = *(const short8*)&sA[row * 64 + jc * 8];
      }
#pragma unroll
      for (int n = 0; n < 4; ++n) {
        int row = wn + n * 16 + r16;
        int jc = (kk * 4 + kg) ^ (row & 7);
        bfr[n] = *(const short8*)&sB[row * 64 + jc * 8];
      }
#pragma unroll
      for (int m = 0; m < 4; ++m)
#pragma unroll
        for (int n = 0; n < 4; ++n)
          acc[m][n] = __builtin_amdgcn_mfma_f32_16x16x32_bf16(af[m], bfr[n], acc[m][n], 0, 0, 0);
    }
    __syncthreads();  // all ds_reads done before next stage overwrites
  }

  // epilogue: C/D layout col = lane&15, row = (lane>>4)*4 + reg  [m89/m91]
#pragma unroll
  for (int m = 0; m < 4; ++m) {
    int rbase = m0 + wm + m * 16 + kg * 4;
#pragma unroll
    for (int n = 0; n < 4; ++n) {
      int col = n0 + wn + n * 16 + r16;
      float bcol = bias[col];
#pragma unroll
      for (int r = 0; r < 4; ++r) {
        int grow = rbase + r;
        float g = gate4[(size_t)grow * 4];
        float v = acc[m][n][r];
        if (MODE == 1) {
          v += bcol;
          v = fmaxf(v, 0.f);
          v *= g;
          OutB[(size_t)grow * ldc + col] = f2bf(v);
        } else {
          v += g * bcol;
          size_t oi = (size_t)grow * ldc + col;
          if (accumulate) v += FOut[oi];
          FOut[oi] = v;
        }
      }
    }
  }
}

extern "C" void kernel_launch(void* const* d_in, const int* in_sizes, int n_in,
                              void* d_out, int out_size, void* d_ws, size_t ws_size,
                              hipStream_t stream) {
  const float* q  = (const float*)d_in[0];
  const float* k  = (const float*)d_in[1];
  const float* W1 = (const float*)d_in[2];
  const float* b1 = (const float*)d_in[3];
  const float* W2 = (const float*)d_in[4];
  const float* b2 = (const float*)d_in[5];
  const float* Wg = (const float*)d_in[6];
  const float* bg = (const float*)d_in[7];
  float* out = (float*)d_out;

  char* ws = (char*)d_ws;
  size_t off = 0;
  float* gate = (float*)(ws + off); off += (size_t)N_TOK * 4 * sizeof(float);
  short* qb   = (short*)(ws + off); off += (size_t)N_TOK * DIM * 2;
  short* W1t  = (short*)(ws + off); off += (size_t)NEXP * (size_t)DIM * HID * 2;  // [E][H][D]
  short* W2t  = (short*)(ws + off); off += (size_t)NEXP * (size_t)HID * DIM * 2;  // [E][D][H]
  const size_t fixed = off;

  gate_kernel<<<dim3(N_TOK / 4), dim3(256), 0, stream>>>(q, k, Wg, bg, gate);
  convert_bf16_kernel<<<dim3(2048), dim3(256), 0, stream>>>(q, qb, N_TOK * DIM / 4);
  // W1 [E][D][H] -> W1t [E][H][D]
  transpose_bf16_kernel<<<dim3(HID / 64, DIM / 64, NEXP), dim3(256), 0, stream>>>(W1, W1t, DIM, HID);
  // W2 [E][H][D] -> W2t [E][D][H]
  transpose_bf16_kernel<<<dim3(DIM / 64, HID / 64, NEXP), dim3(256), 0, stream>>>(W2, W2t, HID, DIM);

  size_t avail = (ws_size > fixed) ? ws_size - fixed : 0;

  if ((size_t)N_TOK * HID * 2 <= avail) {
    // full-M per-expert (Hs = [N_TOK][HID] reused across experts)
    short* Hs = (short*)(ws + fixed);
    for (int e = 0; e < NEXP; ++e) {
      gemm_kernel<1><<<dim3((N_TOK / 128) * (HID / 128)), dim3(256), 0, stream>>>(
          qb, W1t + (size_t)e * HID * DIM, DIM, HID / 128,
          b1 + (size_t)e * HID, gate + e, Hs, nullptr, HID, 0);
      gemm_kernel<2><<<dim3((N_TOK / 128) * (DIM / 128)), dim3(256), 0, stream>>>(
          Hs, W2t + (size_t)e * DIM * HID, HID, DIM / 128,
          b2 + (size_t)e * DIM, gate + e, nullptr, out, DIM, e > 0);
    }
  } else {
    // row-chunked per-expert fallback (tiny ws) — identity mapping path in-kernel
    short* Hs = (short*)(ws + fixed);
    long long mc = (long long)(avail / ((size_t)HID * 2));
    mc &= ~127LL;
    if (mc < 128) mc = 128;
    if (mc > N_TOK) mc = N_TOK;
    for (int cb = 0; cb < N_TOK; cb += (int)mc) {
      int rows = (N_TOK - cb < (int)mc) ? (N_TOK - cb) : (int)mc;
      for (int e = 0; e < NEXP; ++e) {
        gemm_kernel<1><<<dim3((rows / 128) * (HID / 128)), dim3(256), 0, stream>>>(
            qb + (size_t)cb * DIM, W1t + (size_t)e * HID * DIM, DIM, HID / 128,
            b1 + (size_t)e * HID, gate + (size_t)cb * 4 + e, Hs, nullptr, HID, 0);
        gemm_kernel<2><<<dim3((rows / 128) * (DIM / 128)), dim3(256), 0, stream>>>(
            Hs, W2t + (size_t)e * DIM * HID, HID, DIM / 128,
            b2 + (size_t)e * DIM, gate + (size_t)cb * 4 + e, nullptr,
            out + (size_t)cb * DIM, DIM, e > 0);
      }
    }
  }
}

// Round 8
// 1276.697 us; speedup vs baseline: 1.3403x; 1.0041x over previous
//
#include <hip/hip_runtime.h>
#include <hip/hip_bf16.h>

#define N_TOK 16384
#define DIM   1024
#define NEXP  4
#define HID   4096
#define CHK   8192   // token half-chunk for the G1/G2 software pipeline

typedef __attribute__((ext_vector_type(8))) short short8;
typedef __attribute__((ext_vector_type(4))) short short4v;
typedef __attribute__((ext_vector_type(4))) float float4v;

static __device__ __forceinline__ short f2bf(float f) {
  __hip_bfloat16 h = __float2bfloat16(f);
  return *reinterpret_cast<short*>(&h);
}

#define GLOAD_LDS16(gsrc, ldst)                                                            \
  __builtin_amdgcn_global_load_lds((const __attribute__((address_space(1))) void*)(gsrc),  \
                                   (__attribute__((address_space(3))) void*)(ldst), 16, 0, 0)

// -------- fused gate (softmax(concat(q,k)@Wg+bg)) + q->bf16 convert: q read once --------
__global__ void gatecvt_kernel(const float* __restrict__ q, const float* __restrict__ k,
                               const float* __restrict__ Wg, const float* __restrict__ bg,
                               float* __restrict__ gate, short* __restrict__ qb) {
  const int wave = threadIdx.x >> 6, lane = threadIdx.x & 63;
  const int n = blockIdx.x * 4 + wave;
  const float* qr = q + (size_t)n * DIM;
  const float* kr = k + (size_t)n * DIM;
  short* qbr = qb + (size_t)n * DIM;
  float s0 = 0.f, s1 = 0.f, s2 = 0.f, s3 = 0.f;
#pragma unroll
  for (int it = 0; it < 4; ++it) {
    int d = it * 256 + lane * 4;
    float4 qv = *(const float4*)(qr + d);
    float4 kv = *(const float4*)(kr + d);
    short4v o;
    o[0] = f2bf(qv.x); o[1] = f2bf(qv.y); o[2] = f2bf(qv.z); o[3] = f2bf(qv.w);
    *(short4v*)(qbr + d) = o;
    const float xq[4] = {qv.x, qv.y, qv.z, qv.w};
    const float xk[4] = {kv.x, kv.y, kv.z, kv.w};
#pragma unroll
    for (int j = 0; j < 4; ++j) {
      float4 w = *(const float4*)(Wg + (size_t)(d + j) * 4);
      s0 += xq[j] * w.x; s1 += xq[j] * w.y; s2 += xq[j] * w.z; s3 += xq[j] * w.w;
      float4 w2 = *(const float4*)(Wg + (size_t)(DIM + d + j) * 4);
      s0 += xk[j] * w2.x; s1 += xk[j] * w2.y; s2 += xk[j] * w2.z; s3 += xk[j] * w2.w;
    }
  }
  for (int off = 32; off; off >>= 1) {
    s0 += __shfl_xor(s0, off);
    s1 += __shfl_xor(s1, off);
    s2 += __shfl_xor(s2, off);
    s3 += __shfl_xor(s3, off);
  }
  if (lane == 0) {
    float l0 = s0 + bg[0], l1 = s1 + bg[1], l2 = s2 + bg[2], l3 = s3 + bg[3];
    float m = fmaxf(fmaxf(l0, l1), fmaxf(l2, l3));
    float e0 = expf(l0 - m), e1 = expf(l1 - m), e2 = expf(l2 - m), e3 = expf(l3 - m);
    float inv = 1.f / (e0 + e1 + e2 + e3);
    float4 g; g.x = e0 * inv; g.y = e1 * inv; g.z = e2 * inv; g.w = e3 * inv;
    *(float4*)(gate + (size_t)n * 4) = g;
  }
}

// ---- LDS-tiled transpose+convert: in[z][R][C] f32 -> out[z][C][R] bf16 (per-z contiguous) ----
__global__ void transpose_bf16_kernel(const float* __restrict__ in, short* __restrict__ out,
                                      int R, int C) {
  __shared__ float tile[64][65];
  const size_t eoff = (size_t)blockIdx.z * (size_t)R * C;
  const float* src = in + eoff;
  short* dst = out + eoff;
  const int r0 = blockIdx.y * 64, c0 = blockIdx.x * 64;
  const int tc = threadIdx.x & 63, tr = threadIdx.x >> 6;
#pragma unroll
  for (int p = 0; p < 16; ++p) {
    int r = p * 4 + tr;
    tile[r][tc] = src[(size_t)(r0 + r) * C + (c0 + tc)];
  }
  __syncthreads();
#pragma unroll
  for (int p = 0; p < 16; ++p) {
    int i = p * 4 + tr;
    dst[(size_t)(c0 + i) * R + (r0 + tc)] = f2bf(tile[tc][i]);
  }
}

// ----- R7-proven GEMM body: C = A[M,K] @ Bt[N,K]^T, 128x128 tile, BK=64, 16x16x32 frags -----
// 2-barrier loop, global_load_lds staging, chunk^=(row&7) swizzle (0 conflicts measured),
// XCD-locality tile order (fetch 568->183 MB measured). Strides: lda = ldb = K.
// MODE 1: OutB[row,col] = bf16( gate4[row*4] * relu(C + bias[col]) )   (gate4 = gate+cb*4+e)
// MODE 2: FOut[row,col] (+)= C + gate4[row*4]*bias[col]
template <int MODE>
__device__ __forceinline__ void gemm_body(short* sA, short* sB,
                                          const short* __restrict__ A, const short* __restrict__ Bt,
                                          int K, int NTM, int NTN, int bid,
                                          const float* __restrict__ bias,
                                          const float* __restrict__ gate4,
                                          short* __restrict__ OutB, float* __restrict__ FOut,
                                          int ldc, int accumulate) {
  int tile_m, tile_n;
  {
    const int m_own = NTM >> 3;
    const int xcd = bid & 7;
    const int idx = bid >> 3;
    const int mgrp = (m_own < 8) ? m_own : 8;
    const int per = mgrp * 4;
    const int pos = idx % per;
    const int chunk = idx / per;
    const int ml = pos % mgrp;
    const int nl = pos / mgrp;
    const int nchunks = NTN >> 2;
    const int nc = chunk % nchunks;
    const int mg2 = chunk / nchunks;
    tile_m = xcd * m_own + mg2 * mgrp + ml;
    tile_n = nc * 4 + nl;
  }
  const int m0 = tile_m * 128;
  const int n0 = tile_n * 128;

  const int t = threadIdx.x;
  const int lane = t & 63;
  const int wave = t >> 6;
  const int wm = (wave >> 1) * 64;
  const int wn = (wave & 1) * 64;
  const int r16 = lane & 15;
  const int kg = lane >> 4;

  float4v acc[4][4];
#pragma unroll
  for (int m = 0; m < 4; ++m)
#pragma unroll
    for (int n = 0; n < 4; ++n) acc[m][n] = (float4v)0.0f;

  for (int k0 = 0; k0 < K; k0 += 64) {
#pragma unroll
    for (int i = 0; i < 4; ++i) {
      int c = i * 256 + t;
      int row = c >> 3;
      int jc = (c & 7) ^ (row & 7);
      GLOAD_LDS16(A + (size_t)(m0 + row) * K + k0 + jc * 8, &sA[c * 8]);
      GLOAD_LDS16(Bt + (size_t)(n0 + row) * K + k0 + jc * 8, &sB[c * 8]);
    }
    __syncthreads();
#pragma unroll
    for (int kk = 0; kk < 2; ++kk) {
      short8 af[4], bfr[4];
#pragma unroll
      for (int m = 0; m < 4; ++m) {
        int row = wm + m * 16 + r16;
        int jc = (kk * 4 + kg) ^ (row & 7);
        af[m] = *(const short8*)&sA[row * 64 + jc * 8];
      }
#pragma unroll
      for (int n = 0; n < 4; ++n) {
        int row = wn + n * 16 + r16;
        int jc = (kk * 4 + kg) ^ (row & 7);
        bfr[n] = *(const short8*)&sB[row * 64 + jc * 8];
      }
#pragma unroll
      for (int m = 0; m < 4; ++m)
#pragma unroll
        for (int n = 0; n < 4; ++n)
          acc[m][n] = __builtin_amdgcn_mfma_f32_16x16x32_bf16(af[m], bfr[n], acc[m][n], 0, 0, 0);
    }
    __syncthreads();
  }

  // epilogue: C/D layout col = lane&15, row = (lane>>4)*4 + reg  [m89/m91]
#pragma unroll
  for (int m = 0; m < 4; ++m) {
    int rbase = m0 + wm + m * 16 + kg * 4;
#pragma unroll
    for (int n = 0; n < 4; ++n) {
      int col = n0 + wn + n * 16 + r16;
      float bcol = bias[col];
#pragma unroll
      for (int r = 0; r < 4; ++r) {
        int grow = rbase + r;
        float g = gate4[(size_t)grow * 4];
        float v = acc[m][n][r];
        if (MODE == 1) {
          v += bcol;
          v = fmaxf(v, 0.f);
          v *= g;
          OutB[(size_t)grow * ldc + col] = f2bf(v);
        } else {
          v += g * bcol;
          size_t oi = (size_t)grow * ldc + col;
          if (accumulate) v += FOut[oi];
          FOut[oi] = v;
        }
      }
    }
  }
}

// ------- fused co-scheduled dispatch: blocks [0,g2n) run GEMM2(chunk), rest GEMM1(chunk) ----
// G2 blocks (long, K=4096) get low blockIdx -> dispatched first; 2048 short G1 blocks
// (K=1024) backfill the CUs -> kills the ragged-round idle of separate dispatches.
__global__ __launch_bounds__(256, 2)
void fused_kernel(const short* __restrict__ g1A, const short* __restrict__ g1B,
                  const float* __restrict__ g1bias, const float* __restrict__ g1gate,
                  short* __restrict__ g1out,
                  const short* __restrict__ g2A, const short* __restrict__ g2B,
                  const float* __restrict__ g2bias, const float* __restrict__ g2gate,
                  float* __restrict__ g2out, int g2accum, int g2n) {
  __shared__ short sA[128 * 64];
  __shared__ short sB[128 * 64];
  if ((int)blockIdx.x < g2n) {
    gemm_body<2>(sA, sB, g2A, g2B, HID, CHK / 128, DIM / 128, blockIdx.x,
                 g2bias, g2gate, nullptr, g2out, DIM, g2accum);
  } else {
    gemm_body<1>(sA, sB, g1A, g1B, DIM, CHK / 128, HID / 128, blockIdx.x - g2n,
                 g1bias, g1gate, g1out, nullptr, HID, 0);
  }
}

// ---------------- standalone GEMM (fallback path), grid = NTM*NTN ----------------
template <int MODE>
__global__ __launch_bounds__(256, 2)
void gemm_kernel(const short* __restrict__ A, const short* __restrict__ Bt, int K, int NTN,
                 const float* __restrict__ bias, const float* __restrict__ gate4,
                 short* __restrict__ OutB, float* __restrict__ FOut, int ldc, int accumulate) {
  __shared__ short sA[128 * 64];
  __shared__ short sB[128 * 64];
  gemm_body<MODE>(sA, sB, A, Bt, K, gridDim.x / NTN, NTN, blockIdx.x,
                  bias, gate4, OutB, FOut, ldc, accumulate);
}

extern "C" void kernel_launch(void* const* d_in, const int* in_sizes, int n_in,
                              void* d_out, int out_size, void* d_ws, size_t ws_size,
                              hipStream_t stream) {
  const float* q  = (const float*)d_in[0];
  const float* k  = (const float*)d_in[1];
  const float* W1 = (const float*)d_in[2];
  const float* b1 = (const float*)d_in[3];
  const float* W2 = (const float*)d_in[4];
  const float* b2 = (const float*)d_in[5];
  const float* Wg = (const float*)d_in[6];
  const float* bg = (const float*)d_in[7];
  float* out = (float*)d_out;

  char* ws = (char*)d_ws;
  size_t off = 0;
  float* gate = (float*)(ws + off); off += (size_t)N_TOK * 4 * sizeof(float);
  short* qb   = (short*)(ws + off); off += (size_t)N_TOK * DIM * 2;
  short* W1t  = (short*)(ws + off); off += (size_t)NEXP * (size_t)DIM * HID * 2;  // [E][H][D]
  short* W2t  = (short*)(ws + off); off += (size_t)NEXP * (size_t)HID * DIM * 2;  // [E][D][H]
  const size_t fixed = off;

  gatecvt_kernel<<<dim3(N_TOK / 4), dim3(256), 0, stream>>>(q, k, Wg, bg, gate, qb);
  transpose_bf16_kernel<<<dim3(HID / 64, DIM / 64, NEXP), dim3(256), 0, stream>>>(W1, W1t, DIM, HID);
  transpose_bf16_kernel<<<dim3(DIM / 64, HID / 64, NEXP), dim3(256), 0, stream>>>(W2, W2t, HID, DIM);

  size_t avail = (ws_size > fixed) ? ws_size - fixed : 0;
  const size_t hs_half = (size_t)CHK * HID * 2;  // 64 MB

  if (2 * hs_half <= avail) {
    // ---- software pipeline: 9 dispatches; G2(chunk i, e) co-scheduled with G1(chunk j, e') ---
    short* HsA = (short*)(ws + fixed);
    short* HsB = (short*)(ws + fixed + hs_half);
    short* hs[2] = {HsA, HsB};
    const int G1BLK = (CHK / 128) * (HID / 128);  // 2048
    const int G2BLK = (CHK / 128) * (DIM / 128);  // 512

    // d0: G1(c0, e0) -> HsA
    fused_kernel<<<dim3(G1BLK), dim3(256), 0, stream>>>(
        qb, W1t, b1, gate, HsA,
        nullptr, nullptr, nullptr, nullptr, nullptr, 0, 0);
    // d1..d7: step s covers G1(c=(s+1)&1, e=(s+1)>>1) and G2(c=s&1, e=s>>1)
    for (int s = 0; s < 7; ++s) {
      const int c1 = (s + 1) & 1, e1 = (s + 1) >> 1;   // G1 target
      const int c2 = s & 1,       e2 = s >> 1;         // G2 source
      fused_kernel<<<dim3(G2BLK + G1BLK), dim3(256), 0, stream>>>(
          qb + (size_t)c1 * CHK * DIM, W1t + (size_t)e1 * HID * DIM,
          b1 + (size_t)e1 * HID, gate + (size_t)c1 * CHK * 4 + e1, hs[c1],
          hs[c2], W2t + (size_t)e2 * DIM * HID,
          b2 + (size_t)e2 * DIM, gate + (size_t)c2 * CHK * 4 + e2,
          out + (size_t)c2 * CHK * DIM, (e2 > 0) ? 1 : 0, G2BLK);
    }
    // d8: G2(c1, e3) from HsB
    fused_kernel<<<dim3(G2BLK), dim3(256), 0, stream>>>(
        nullptr, nullptr, nullptr, nullptr, nullptr,
        hs[1], W2t + (size_t)3 * DIM * HID, b2 + (size_t)3 * DIM,
        gate + (size_t)CHK * 4 + 3, out + (size_t)CHK * DIM, 1, G2BLK);
  } else {
    // row-chunked per-expert fallback (tiny ws)
    short* Hs = (short*)(ws + fixed);
    long long mc = (long long)(avail / ((size_t)HID * 2));
    mc &= ~127LL;
    if (mc < 128) mc = 128;
    if (mc > N_TOK) mc = N_TOK;
    for (int cb = 0; cb < N_TOK; cb += (int)mc) {
      int rows = (N_TOK - cb < (int)mc) ? (N_TOK - cb) : (int)mc;
      for (int e = 0; e < NEXP; ++e) {
        gemm_kernel<1><<<dim3((rows / 128) * (HID / 128)), dim3(256), 0, stream>>>(
            qb + (size_t)cb * DIM, W1t + (size_t)e * HID * DIM, DIM, HID / 128,
            b1 + (size_t)e * HID, gate + (size_t)cb * 4 + e, Hs, nullptr, HID, 0);
        gemm_kernel<2><<<dim3((rows / 128) * (DIM / 128)), dim3(256), 0, stream>>>(
            Hs, W2t + (size_t)e * DIM * HID, HID, DIM / 128,
            b2 + (size_t)e * DIM, gate + (size_t)cb * 4 + e, nullptr,
            out + (size_t)cb * DIM, DIM, e > 0);
      }
    }
  }
}